// Round 10
// baseline (161.717 us; speedup 1.0000x reference)
//
#include <hip/hip_runtime.h>
#include <hip/hip_bf16.h>
#include <stdint.h>

// Problem constants (b=16, l=4096, d=256, c=256, qk_dim=256, heads=8)
// Inputs: float32. Outputs: FLOAT32:
//   out[0..65536)       k  [8,256,32]
//   out[65536..131072)  v  [8,256,32]
//   out[131072..196608) x_global [256,256]
#define DD 256
#define CC 256
#define MAXN 1024   // per-cluster list slab (mean 256, std ~16; 1024 is >40 sigma)

typedef __attribute__((ext_vector_type(8))) short bf16x8;
typedef __attribute__((ext_vector_type(4))) float f32x4;

// round-to-nearest-even f32 -> bf16; also returns the rounded value as f32
__device__ __forceinline__ unsigned short bf16_rn(float v, float& hval) {
    unsigned u = __builtin_bit_cast(unsigned, v);
    unsigned r = u + 0x7FFFu + ((u >> 16) & 1u);
    hval = __builtin_bit_cast(float, r & 0xFFFF0000u);
    return (unsigned short)(r >> 16);
}

// pack {hi16(b):hi16(a)} into one u32 (a -> low half) -- 1 v_perm_b32
__device__ __forceinline__ unsigned pack2h(unsigned a, unsigned b) {
#if __has_builtin(__builtin_amdgcn_perm)
    return __builtin_amdgcn_perm(b, a, 0x07060302u);
#else
    return (a >> 16) | (b & 0xFFFF0000u);
#endif
}

// cheap split-bf16 conversion (R3): hi = RN-bf16(x); lo = TRUNC-bf16(x-hi).
// Trunc-lo perturbs dots at 2^-17 rel; absmax 3.9e-3 passed R4-R9, determin.
__device__ __forceinline__ void cvt_split(const float4& a, const float4& b,
                                          bf16x8& hi, bf16x8& lo) {
    float f[8] = {a.x, a.y, a.z, a.w, b.x, b.y, b.z, b.w};
    unsigned hp[4], lp[4];
#pragma unroll
    for (int i = 0; i < 4; i++) {
        unsigned u0 = __builtin_bit_cast(unsigned, f[2 * i]);
        unsigned u1 = __builtin_bit_cast(unsigned, f[2 * i + 1]);
        unsigned r0 = u0 + 0x7FFFu + ((u0 >> 16) & 1u);
        unsigned r1 = u1 + 0x7FFFu + ((u1 >> 16) & 1u);
        hp[i] = pack2h(r0, r1);
        float h0 = __builtin_bit_cast(float, r0 & 0xFFFF0000u);
        float h1 = __builtin_bit_cast(float, r1 & 0xFFFF0000u);
        unsigned l0 = __builtin_bit_cast(unsigned, f[2 * i] - h0);
        unsigned l1 = __builtin_bit_cast(unsigned, f[2 * i + 1] - h1);
        lp[i] = pack2h(l0, l1);
    }
    uint4 H = {hp[0], hp[1], hp[2], hp[3]};
    uint4 L = {lp[0], lp[1], lp[2], lp[3]};
    hi = __builtin_bit_cast(bf16x8, H);
    lo = __builtin_bit_cast(bf16x8, L);
}

// ---------------------------------------------------------------------------
// K1: normalize means; emit split-bf16 packed per 64-cluster GROUP:
//   mpk2[g(4)][ hi: [kc(8)][q(4)][ct(4)][m(16)][8] | lo: same ] (64KB/g)
// cluster c = g*64 + ct*16 + m ; dim d = kc*32 + q*8 + j.  Also zero bins.
__global__ __launch_bounds__(256) void k_prep(const float* __restrict__ xm,
                                              float* __restrict__ means_n,
                                              unsigned short* __restrict__ mpk2,
                                              int* __restrict__ bins) {
    __shared__ float red[256];
    int c = blockIdx.x, t = threadIdx.x;
    float v = xm[c * DD + t];
    red[t] = v * v;
    __syncthreads();
    for (int off = 128; off > 0; off >>= 1) {
        if (t < off) red[t] += red[t + off];
        __syncthreads();
    }
    float inv = 1.0f / fmaxf(sqrtf(red[0]), 1e-12f);
    float vn = v * inv;
    means_n[c * DD + t] = vn;
    float hf; unsigned short hb = bf16_rn(vn, hf);
    float lo = vn - hf;                 // exact
    float d2; unsigned short lb = bf16_rn(lo, d2);
    int g = c >> 6, ct = (c >> 4) & 3, m = c & 15;
    int kc = t >> 5, q = (t >> 3) & 3, j = t & 7;
    size_t base = (size_t)g * 32768 + ((kc * 4 + q) * 64 + ct * 16 + m) * 8 + j;
    mpk2[base]         = hb;            // hi half
    mpk2[base + 16384] = lb;            // lo half
    if (c == 0) bins[t] = 0;
}

// ---------------------------------------------------------------------------
// K2 v13 (R10): R9 structure + phase-B software pipeline with ASM-PINNED
// B-fragment prefetch. R9 post-mortem: DMA-staged phase A was NEUTRAL
// (42us, VGPR 104 unchanged) -> phase B's ds_read->MFMA chain is the cost
// (~240cyc/kc serial, only 2 waves/SIMD to hide it). R7's prefetch test was
// confounded by the xv[32] change; this isolates it, with
// asm volatile("" :: "v"(frag)) forcing the kc+1 loads to ISSUE before the
// kc MFMA block (compiler cannot re-sink past an asm input use).
// Numerics bit-identical to R6/R9.
__global__ __launch_bounds__(512, 2) void k_assign(
        const float* __restrict__ x,
        const unsigned short* __restrict__ mpk2,
        unsigned short* __restrict__ bkts,
        float* __restrict__ inv_norm) {
    __shared__ __align__(16) unsigned short mlds[2][32768];   // 2 x 64KB
    int t = threadIdx.x;
    int w = t >> 6, lane = t & 63;             // w in 0..7
    int m = lane & 15, q = lane >> 4;          // q in 0..3
    int bp0 = blockIdx.x * 256;
    int p0 = bp0 + w * 32;
    int pt0 = w * 4 + q;                       // DMA: point for i=0
    int sg  = m ^ (pt0 & 15);                  // pre-swizzled source seg
    int ptl0 = w * 32 + m, ptl1 = ptl0 + 16;   // reader: this wave's rows

#define DMA_X(cc, bb) {                                                        \
    const float* s0_ = x + (size_t)(bp0 + pt0) * DD + (cc) * 64 + sg * 4;      \
    _Pragma("unroll")                                                          \
    for (int i = 0; i < 8; i++)                                                \
        __builtin_amdgcn_global_load_lds(                                      \
            (const __attribute__((address_space(1))) void*)(s0_ + (size_t)i * 32 * DD), \
            (__attribute__((address_space(3))) void*)(&mlds[bb][i * 4096 + w * 512]),   \
            16, 0, 0); }

#define READ_CVT(cc, bb) {                                                     \
    const float* lf_ = (const float*)&mlds[bb][0];                             \
    _Pragma("unroll")                                                          \
    for (int kcp = 0; kcp < 2; kcp++) {                                        \
        int kc_ = (cc) * 2 + kcp;                                              \
        int s0_ = 2 * q + 8 * kcp;                                             \
        float4 xa0 = *(const float4*)(lf_ + ptl0 * 64 + ((s0_    ) ^ m) * 4);  \
        float4 xb0 = *(const float4*)(lf_ + ptl0 * 64 + ((s0_ + 1) ^ m) * 4);  \
        float4 xa1 = *(const float4*)(lf_ + ptl1 * 64 + ((s0_    ) ^ m) * 4);  \
        float4 xb1 = *(const float4*)(lf_ + ptl1 * 64 + ((s0_ + 1) ^ m) * 4);  \
        ss0 += xa0.x * xa0.x + xa0.y * xa0.y + xa0.z * xa0.z + xa0.w * xa0.w + \
               xb0.x * xb0.x + xb0.y * xb0.y + xb0.z * xb0.z + xb0.w * xb0.w;  \
        ss1 += xa1.x * xa1.x + xa1.y * xa1.y + xa1.z * xa1.z + xa1.w * xa1.w + \
               xb1.x * xb1.x + xb1.y * xb1.y + xb1.z * xb1.z + xb1.w * xb1.w;  \
        cvt_split(xa0, xb0, ah0[kc_], al0[kc_]);                               \
        cvt_split(xa1, xb1, ah1[kc_], al1[kc_]); } }

#define DMA_MEANS(gg, bb) {                                                    \
    const unsigned short* gm_ = mpk2 + (size_t)(gg) * 32768 + w * 4096 + lane * 8; \
    _Pragma("unroll")                                                          \
    for (int i = 0; i < 8; i++)                                                \
        __builtin_amdgcn_global_load_lds(                                      \
            (const __attribute__((address_space(1))) void*)(gm_ + i * 512),    \
            (__attribute__((address_space(3))) void*)(&mlds[bb][w * 4096 + i * 512]), \
            16, 0, 0); }

    bf16x8 ah0[8], al0[8], ah1[8], al1[8];
    float ss0 = 0.f, ss1 = 0.f;

    // phase A: DMA-staged x load+convert, ping-pong B0/B1
    DMA_X(0, 0);
    DMA_X(1, 1);
    __syncthreads();            // c0,c1 ready (vmcnt drained by barrier)
    READ_CVT(0, 0);
    __syncthreads();            // all waves done reading B0
    DMA_X(2, 0);
    READ_CVT(1, 1);
    __syncthreads();            // B1 free + c2 ready
    DMA_X(3, 1);
    READ_CVT(2, 0);
    __syncthreads();            // B0 free + c3 ready
    DMA_MEANS(0, 0);
    READ_CVT(3, 1);

    // row inv-norms (each point handled exactly once chip-wide)
    ss0 += __shfl_xor(ss0, 16, 64); ss0 += __shfl_xor(ss0, 32, 64);
    ss1 += __shfl_xor(ss1, 16, 64); ss1 += __shfl_xor(ss1, 32, 64);
    if (q == 0) {
        inv_norm[p0 + m]      = 1.0f / fmaxf(sqrtf(ss0), 1e-12f);
        inv_norm[p0 + 16 + m] = 1.0f / fmaxf(sqrtf(ss1), 1e-12f);
    }
    __syncthreads();            // group-0 means ready, B1 free

    float bv0[4], bv1[4]; int bi0[4], bi1[4];
#pragma unroll
    for (int r = 0; r < 4; r++) {
        bv0[r] = -__builtin_inff(); bi0[r] = 0;
        bv1[r] = -__builtin_inff(); bi1[r] = 0;
    }

    for (int g = 0; g < 4; g++) {
        // prefetch next group's 64KB into the other buffer
        if (g < 3) { DMA_MEANS(g + 1, (g + 1) & 1); }

        f32x4 acc0[4], acc1[4];
#pragma unroll
        for (int ct = 0; ct < 4; ct++) {
            acc0[ct] = (f32x4){0.f, 0.f, 0.f, 0.f};
            acc1[ct] = (f32x4){0.f, 0.f, 0.f, 0.f};
        }
        const unsigned short* mb = &mlds[g & 1][q * 512 + m * 8];

        // kc=0 fragments
        bf16x8 bh[4], bl[4];
#pragma unroll
        for (int ct = 0; ct < 4; ct++) {
            bh[ct] = *(const bf16x8*)(mb + ct * 128);
            bl[ct] = *(const bf16x8*)(mb + 16384 + ct * 128);
        }
#pragma unroll
        for (int kc = 0; kc < 8; kc++) {
            // issue kc+1's 8 ds_read_b128, then PIN them with an asm input
            // use so the compiler cannot sink the loads below the MFMAs.
            bf16x8 nh[4], nl[4];
            if (kc < 7) {
                const unsigned short* fb = mb + (kc + 1) * 2048;
#pragma unroll
                for (int ct = 0; ct < 4; ct++) {
                    nh[ct] = *(const bf16x8*)(fb + ct * 128);
                    nl[ct] = *(const bf16x8*)(fb + 16384 + ct * 128);
                }
                asm volatile("" :: "v"(nh[0]), "v"(nh[1]), "v"(nh[2]), "v"(nh[3]),
                                   "v"(nl[0]), "v"(nl[1]), "v"(nl[2]), "v"(nl[3]));
            }
#pragma unroll
            for (int ct = 0; ct < 4; ct++) {
                acc0[ct] = __builtin_amdgcn_mfma_f32_16x16x32_bf16(ah0[kc], bh[ct], acc0[ct], 0, 0, 0);
                acc0[ct] = __builtin_amdgcn_mfma_f32_16x16x32_bf16(al0[kc], bh[ct], acc0[ct], 0, 0, 0);
                acc0[ct] = __builtin_amdgcn_mfma_f32_16x16x32_bf16(ah0[kc], bl[ct], acc0[ct], 0, 0, 0);
                acc1[ct] = __builtin_amdgcn_mfma_f32_16x16x32_bf16(ah1[kc], bh[ct], acc1[ct], 0, 0, 0);
                acc1[ct] = __builtin_amdgcn_mfma_f32_16x16x32_bf16(al1[kc], bh[ct], acc1[ct], 0, 0, 0);
                acc1[ct] = __builtin_amdgcn_mfma_f32_16x16x32_bf16(ah1[kc], bl[ct], acc1[ct], 0, 0, 0);
            }
            if (kc < 7) {
#pragma unroll
                for (int ct = 0; ct < 4; ct++) { bh[ct] = nh[ct]; bl[ct] = nl[ct]; }
            }
        }

        // per-lane argmax update (ascending g, ascending ct; strict > keeps
        // the lowest cluster index among exact ties)
#pragma unroll
        for (int ct = 0; ct < 4; ct++) {
            int cbase = g * 64 + ct * 16 + m;
#pragma unroll
            for (int r = 0; r < 4; r++) {
                float v2 = acc0[ct][r];
                if (v2 > bv0[r]) { bv0[r] = v2; bi0[r] = cbase; }
                float v3 = acc1[ct][r];
                if (v3 > bv1[r]) { bv1[r] = v3; bi1[r] = cbase; }
            }
        }
        __syncthreads();   // next-group stage complete; buffer safe to reuse
    }

    // reduce across the 16 m-lanes; tie -> lowest cluster index
#pragma unroll
    for (int mask = 1; mask < 16; mask <<= 1) {
#pragma unroll
        for (int r = 0; r < 4; r++) {
            float ov = __shfl_xor(bv0[r], mask, 64);
            int   oi = __shfl_xor(bi0[r], mask, 64);
            if (ov > bv0[r] || (ov == bv0[r] && oi < bi0[r])) { bv0[r] = ov; bi0[r] = oi; }
            ov = __shfl_xor(bv1[r], mask, 64);
            oi = __shfl_xor(bi1[r], mask, 64);
            if (ov > bv1[r] || (ov == bv1[r] && oi < bi1[r])) { bv1[r] = ov; bi1[r] = oi; }
        }
    }
    if (m == 0) {
#pragma unroll
        for (int r = 0; r < 4; r++) {
            bkts[p0 + q * 4 + r]      = (unsigned short)bi0[r];
            bkts[p0 + 16 + q * 4 + r] = (unsigned short)bi1[r];
        }
    }
#undef DMA_X
#undef READ_CVT
#undef DMA_MEANS
}

// ---------------------------------------------------------------------------
// K3: sort point indices by bucket (unchanged).
__global__ __launch_bounds__(256) void k_sort(const unsigned short* __restrict__ bkts,
                                              unsigned short* __restrict__ list,
                                              int* __restrict__ bins) {
    __shared__ int hist[256];
    __shared__ int base[256];
    __shared__ unsigned short lpos[1024];
    int t = threadIdx.x;
    hist[t] = 0;
    __syncthreads();
    int p0 = blockIdx.x * 1024;
    int bkt[4];
#pragma unroll
    for (int j = 0; j < 4; j++) {
        int p = p0 + j * 256 + t;
        int b = (int)bkts[p];
        bkt[j] = b;
        lpos[j * 256 + t] = (unsigned short)atomicAdd(&hist[b], 1);
    }
    __syncthreads();
    base[t] = hist[t] > 0 ? atomicAdd(&bins[t], hist[t]) : 0;
    __syncthreads();
#pragma unroll
    for (int j = 0; j < 4; j++) {
        int b = bkt[j];
        int slot = base[b] + (int)lpos[j * 256 + t];
        list[b * MAXN + slot] = (unsigned short)(p0 + j * 256 + t);
    }
}

// ---------------------------------------------------------------------------
// K4: gather partial sums (unchanged from R4). grid (256,4) -> 4 blocks/CU;
// each block writes a NON-atomic partial sum row into dead-workspace aliases.
__global__ __launch_bounds__(256) void k_gather(const float* __restrict__ x,
                                                const unsigned short* __restrict__ list,
                                                const int* __restrict__ bins,
                                                const float* __restrict__ inv_norm,
                                                float* __restrict__ ps0,
                                                float* __restrict__ ps1,
                                                float* __restrict__ ps2,
                                                float* __restrict__ ps3) {
    __shared__ int   plist[256];
    __shared__ float linv[256];
    int c = blockIdx.x, y = blockIdx.y, t = threadIdx.x;
    int cnt = bins[c];
    int i0 = (cnt * y) >> 2, i1 = (cnt * (y + 1)) >> 2;
    int n = i1 - i0;                       // <= 256 (cnt <= MAXN)
    for (int i = t; i < n; i += 256) {
        int p = (int)list[c * MAXN + i0 + i];
        plist[i] = p;
        linv[i]  = inv_norm[p];
    }
    __syncthreads();
    float s = 0.f;
    int i = 0;
    for (; i + 16 <= n; i += 16) {
        float xv[16], lv[16];
#pragma unroll
        for (int j = 0; j < 16; j++) {
            xv[j] = x[(size_t)plist[i + j] * DD + t];
            lv[j] = linv[i + j];
        }
#pragma unroll
        for (int j = 0; j < 16; j++) s += xv[j] * lv[j];
    }
    for (; i < n; i++) s += x[(size_t)plist[i] * DD + t] * linv[i];
    float* base = (y == 0) ? ps0 : (y == 1) ? ps1 : (y == 2) ? ps2 : ps3;
    base[c * DD + t] = s;
}

// ---------------------------------------------------------------------------
// K5: x_global = l2norm(sum of 4 partials) (or old mean if empty bin), then
// k = xg @ Wk^T, v = xg @ Wv^T in [h][c][dh] layout. All f32. 256 blocks.
// NOTE: ps3 aliases out[131072..196608) (x_global). Each thread reads
// ps3[c*DD+t] BEFORE writing out[131072+c*DD+t] at the SAME index -> safe.
__global__ __launch_bounds__(256) void k_xgkv(const float* __restrict__ ps0,
                                              const float* __restrict__ ps1,
                                              const float* __restrict__ ps2,
                                              const float* __restrict__ ps3,
                                              const int* __restrict__ bins,
                                              const float* __restrict__ means_n,
                                              const float* __restrict__ Wk,
                                              const float* __restrict__ Wv,
                                              float* __restrict__ out) {
    __shared__ float red[256];
    __shared__ __align__(16) float xr[256];
    int c = blockIdx.x, t = threadIdx.x;
    float s = ps0[c * DD + t] + ps1[c * DD + t] + ps2[c * DD + t] + ps3[c * DD + t];
    red[t] = s * s;
    __syncthreads();
    for (int off = 128; off > 0; off >>= 1) {
        if (t < off) red[t] += red[t + off];
        __syncthreads();
    }
    float g;
    if (bins[c] > 0) g = s / fmaxf(sqrtf(red[0]), 1e-12f);
    else             g = means_n[c * DD + t];
    out[131072 + c * DD + t] = g;   // output 2: x_global
    xr[t] = g;
    __syncthreads();

    float ak = 0.f, av = 0.f;
    const float4* wkp = (const float4*)(Wk + (size_t)t * DD);
    const float4* wvp = (const float4*)(Wv + (size_t)t * DD);
#pragma unroll 8
    for (int j4 = 0; j4 < 64; j4++) {
        float4 wk = wkp[j4], wv = wvp[j4];
        float4 a = *(const float4*)(xr + j4 * 4);
        ak += a.x * wk.x + a.y * wk.y + a.z * wk.z + a.w * wk.w;
        av += a.x * wv.x + a.y * wv.y + a.z * wv.z + a.w * wv.w;
    }
    int h = t >> 5, dh = t & 31;
    out[h * 8192 + c * 32 + dh]         = ak;   // output 0: k
    out[65536 + h * 8192 + c * 32 + dh] = av;   // output 1: v
}

// ---------------------------------------------------------------------------
extern "C" void kernel_launch(void* const* d_in, const int* in_sizes, int n_in,
                              void* d_out, int out_size, void* d_ws, size_t ws_size,
                              hipStream_t stream) {
    (void)in_sizes; (void)n_in; (void)out_size; (void)ws_size;
    const float* x  = (const float*)d_in[0];  // [16,4096,256] f32
    const float* xm = (const float*)d_in[1];  // [256,256] f32
    const float* Wk = (const float*)d_in[2];  // [256,256] f32
    const float* Wv = (const float*)d_in[3];  // [256,256] f32

    float* ws       = (float*)d_ws;
    float* means_n  = ws;                                        // [0,65536)
    float* inv_norm = ws + 65536;                                // [65536,131072)
    unsigned short* bkts = (unsigned short*)(ws + 131072);       // [131072,163840)
    int*   bins     = (int*)(ws + 262144);                       // [262144,262400)
    unsigned short* mpk2 = (unsigned short*)(ws + 262400);       // [262400,327936)
    unsigned short* list = (unsigned short*)(ws + 327936);       // [327936,459008)
    float* out      = (float*)d_out;
    // partial-sum rows alias memory that is dead by the time k_gather runs:
    float* ps0 = ws + 131072;    // bkts region (dead after k_sort)
    float* ps1 = ws + 196608;    // spare region
    float* ps2 = ws + 262400;    // mpk2 (dead after k_assign)
    float* ps3 = out + 131072;   // x_global slot (k_xgkv reads then overwrites)

    k_prep  <<<256, 256, 0, stream>>>(xm, means_n, mpk2, bins);
    k_assign<<<256, 512, 0, stream>>>(x, mpk2, bkts, inv_norm);
    k_sort  <<<64, 256, 0, stream>>>(bkts, list, bins);
    k_gather<<<dim3(256, 4), 256, 0, stream>>>(x, list, bins, inv_norm, ps0, ps1, ps2, ps3);
    k_xgkv  <<<256, 256, 0, stream>>>(ps0, ps1, ps2, ps3, bins, means_n, Wk, Wv, out);
}

// Round 11
// 158.645 us; speedup vs baseline: 1.0194x; 1.0194x over previous
//
#include <hip/hip_runtime.h>
#include <hip/hip_bf16.h>
#include <stdint.h>

// Problem constants (b=16, l=4096, d=256, c=256, qk_dim=256, heads=8)
// Inputs: float32. Outputs: FLOAT32:
//   out[0..65536)       k  [8,256,32]
//   out[65536..131072)  v  [8,256,32]
//   out[131072..196608) x_global [256,256]
#define DD 256
#define CC 256
#define MAXN 1024   // per-cluster list slab (mean 256, std ~16; 1024 is >40 sigma)

typedef __attribute__((ext_vector_type(8))) short bf16x8;
typedef __attribute__((ext_vector_type(4))) float f32x4;

// round-to-nearest-even f32 -> bf16; also returns the rounded value as f32
__device__ __forceinline__ unsigned short bf16_rn(float v, float& hval) {
    unsigned u = __builtin_bit_cast(unsigned, v);
    unsigned r = u + 0x7FFFu + ((u >> 16) & 1u);
    hval = __builtin_bit_cast(float, r & 0xFFFF0000u);
    return (unsigned short)(r >> 16);
}

// pack {hi16(b):hi16(a)} into one u32 (a -> low half) -- 1 v_perm_b32
__device__ __forceinline__ unsigned pack2h(unsigned a, unsigned b) {
#if __has_builtin(__builtin_amdgcn_perm)
    return __builtin_amdgcn_perm(b, a, 0x07060302u);
#else
    return (a >> 16) | (b & 0xFFFF0000u);
#endif
}

// cheap split-bf16 conversion (R3): hi = RN-bf16(x); lo = TRUNC-bf16(x-hi).
// Trunc-lo perturbs dots at 2^-17 rel; absmax 3.9e-3 passed R4-R10, determin.
__device__ __forceinline__ void cvt_split(const float4& a, const float4& b,
                                          bf16x8& hi, bf16x8& lo) {
    float f[8] = {a.x, a.y, a.z, a.w, b.x, b.y, b.z, b.w};
    unsigned hp[4], lp[4];
#pragma unroll
    for (int i = 0; i < 4; i++) {
        unsigned u0 = __builtin_bit_cast(unsigned, f[2 * i]);
        unsigned u1 = __builtin_bit_cast(unsigned, f[2 * i + 1]);
        unsigned r0 = u0 + 0x7FFFu + ((u0 >> 16) & 1u);
        unsigned r1 = u1 + 0x7FFFu + ((u1 >> 16) & 1u);
        hp[i] = pack2h(r0, r1);
        float h0 = __builtin_bit_cast(float, r0 & 0xFFFF0000u);
        float h1 = __builtin_bit_cast(float, r1 & 0xFFFF0000u);
        unsigned l0 = __builtin_bit_cast(unsigned, f[2 * i] - h0);
        unsigned l1 = __builtin_bit_cast(unsigned, f[2 * i + 1] - h1);
        lp[i] = pack2h(l0, l1);
    }
    uint4 H = {hp[0], hp[1], hp[2], hp[3]};
    uint4 L = {lp[0], lp[1], lp[2], lp[3]};
    hi = __builtin_bit_cast(bf16x8, H);
    lo = __builtin_bit_cast(bf16x8, L);
}

// ---------------------------------------------------------------------------
// K1 (R11 = R8's version): normalize means; split-bf16 packed per 32-cluster
// GROUP (32KB tiles so k_assign can double-buffer in 64KB LDS):
//   mpk2[g(8)][ hi: [kc(8)][q(4)][ct(2)][m(16)][8] | lo: same ]  (32KB/group)
// cluster c = g*32 + ct*16 + m ; dim d = kc*32 + q*8 + j.  Also zero bins.
__global__ __launch_bounds__(256) void k_prep(const float* __restrict__ xm,
                                              float* __restrict__ means_n,
                                              unsigned short* __restrict__ mpk2,
                                              int* __restrict__ bins) {
    __shared__ float red[256];
    int c = blockIdx.x, t = threadIdx.x;
    float v = xm[c * DD + t];
    red[t] = v * v;
    __syncthreads();
    for (int off = 128; off > 0; off >>= 1) {
        if (t < off) red[t] += red[t + off];
        __syncthreads();
    }
    float inv = 1.0f / fmaxf(sqrtf(red[0]), 1e-12f);
    float vn = v * inv;
    means_n[c * DD + t] = vn;
    float hf; unsigned short hb = bf16_rn(vn, hf);
    float lo = vn - hf;                 // exact
    float d2; unsigned short lb = bf16_rn(lo, d2);
    int g = c >> 5, ct = (c >> 4) & 1, m = c & 15;
    int kc = t >> 5, q = (t >> 3) & 3, j = t & 7;
    size_t base = (size_t)g * 16384 + ((kc * 4 + q) * 32 + ct * 16 + m) * 8 + j;
    mpk2[base]        = hb;             // hi half
    mpk2[base + 8192] = lb;             // lo half
    if (c == 0) bins[t] = 0;
}

// ---------------------------------------------------------------------------
// K2 v14 (R11): 4 waves/SIMD WITHOUT spill. R10 post-mortem: asm-pinned
// B-prefetch raised VGPR 104->116 but dur flat 44us -> ds_read latency is
// NOT the wall; with 2 waves/SIMD no pipe exceeds 22%. R8's 4-wave attempt
// spilled because it kept 32 points/wave (128-VGPR frags). v14 halves the
// per-wave footprint instead: wave owns 16 points (1 A-tile, 64-VGPR frags,
// ~115 total); block 512 thr = 128 points; grid 512 = 2 blocks/CU; means in
// 32-cluster groups, 2x32KB LDS dbuf = 64KB/block -> 128KB/CU -> 4 w/SIMD.
// Phase A: R9's DMA ping-pong (4 chunks of 128pt x 64col, XOR-seg swizzle).
// Accumulation & argmax order unchanged -> outputs bit-identical (absmax
// must be exactly 0.00390625 again). Falsifiable: VGPR>125 or WRITE_SIZE
// jump means spill -> revert.
__global__ __launch_bounds__(512, 4) void k_assign(
        const float* __restrict__ x,
        const unsigned short* __restrict__ mpk2,
        unsigned short* __restrict__ bkts,
        float* __restrict__ inv_norm) {
    __shared__ __align__(16) unsigned short mlds[2][16384];   // 2 x 32KB
    int t = threadIdx.x;
    int w = t >> 6, lane = t & 63;             // w in 0..7
    int m = lane & 15, q = lane >> 4;          // q in 0..3
    int bp0 = blockIdx.x * 128;                // block owns 128 points
    int p0 = bp0 + w * 16;                     // wave owns 16 points
    int pt0 = w * 4 + q;                       // DMA: point (mod 32) for i=0
    int sg  = m ^ (pt0 & 15);                  // pre-swizzled source seg
    int ptl = w * 16 + m;                      // reader: this lane's point row

    // DMA chunk cc (128 pts x 64 cols f32 = 32KB) into buffer bb.
    // instr i: lane covers point i*32 + pt0, stored seg m, source seg sg.
#define DMA_X(cc, bb) {                                                        \
    const float* s0_ = x + (size_t)(bp0 + pt0) * DD + (cc) * 64 + sg * 4;      \
    _Pragma("unroll")                                                          \
    for (int i = 0; i < 4; i++)                                                \
        __builtin_amdgcn_global_load_lds(                                      \
            (const __attribute__((address_space(1))) void*)(s0_ + (size_t)i * 32 * DD), \
            (__attribute__((address_space(3))) void*)(&mlds[bb][i * 4096 + w * 512]),   \
            16, 0, 0); }

    // convert chunk cc from buffer bb into frags (2 kc per chunk)
#define READ_CVT(cc, bb) {                                                     \
    const float* lf_ = (const float*)&mlds[bb][0];                             \
    _Pragma("unroll")                                                          \
    for (int kcp = 0; kcp < 2; kcp++) {                                        \
        int kc_ = (cc) * 2 + kcp;                                              \
        int s0_ = 2 * q + 8 * kcp;                                             \
        float4 xa0 = *(const float4*)(lf_ + ptl * 64 + ((s0_    ) ^ m) * 4);   \
        float4 xb0 = *(const float4*)(lf_ + ptl * 64 + ((s0_ + 1) ^ m) * 4);   \
        ss0 += xa0.x * xa0.x + xa0.y * xa0.y + xa0.z * xa0.z + xa0.w * xa0.w + \
               xb0.x * xb0.x + xb0.y * xb0.y + xb0.z * xb0.z + xb0.w * xb0.w;  \
        cvt_split(xa0, xb0, ah[kc_], al[kc_]); } }

#define DMA_MEANS(gg, bb) {                                                    \
    const unsigned short* gm_ = mpk2 + (size_t)(gg) * 16384 + w * 512 + lane * 8; \
    _Pragma("unroll")                                                          \
    for (int i = 0; i < 4; i++)                                                \
        __builtin_amdgcn_global_load_lds(                                      \
            (const __attribute__((address_space(1))) void*)(gm_ + i * 4096),   \
            (__attribute__((address_space(3))) void*)(&mlds[bb][i * 4096 + w * 512]), \
            16, 0, 0); }

    bf16x8 ah[8], al[8];
    float ss0 = 0.f;

    // phase A: DMA-staged x load+convert, ping-pong B0/B1
    DMA_X(0, 0);
    DMA_X(1, 1);
    __syncthreads();            // c0,c1 ready (vmcnt drained by barrier)
    READ_CVT(0, 0);
    __syncthreads();            // all waves done reading B0
    DMA_X(2, 0);
    READ_CVT(1, 1);
    __syncthreads();            // B1 free + c2 ready
    DMA_X(3, 1);
    READ_CVT(2, 0);
    __syncthreads();            // B0 free + c3 ready
    DMA_MEANS(0, 0);
    READ_CVT(3, 1);

    // row inv-norms (each point handled exactly once chip-wide)
    ss0 += __shfl_xor(ss0, 16, 64); ss0 += __shfl_xor(ss0, 32, 64);
    if (q == 0) {
        inv_norm[p0 + m] = 1.0f / fmaxf(sqrtf(ss0), 1e-12f);
    }
    __syncthreads();            // group-0 means ready, B1 free

    float bv[4]; int bi[4];
#pragma unroll
    for (int r = 0; r < 4; r++) { bv[r] = -__builtin_inff(); bi[r] = 0; }

    for (int g = 0; g < 8; g++) {
        // prefetch next group's 32KB into the other buffer
        if (g < 7) { DMA_MEANS(g + 1, (g + 1) & 1); }

        f32x4 acc[2];
        acc[0] = (f32x4){0.f, 0.f, 0.f, 0.f};
        acc[1] = (f32x4){0.f, 0.f, 0.f, 0.f};
        const unsigned short* mb = &mlds[g & 1][q * 256 + m * 8];
#pragma unroll
        for (int kc = 0; kc < 8; kc++) {
            const unsigned short* fb = mb + kc * 1024;
            bf16x8 bh[2], bl[2];
#pragma unroll
            for (int ct = 0; ct < 2; ct++) {   // hoist the 4 ds_read_b128
                bh[ct] = *(const bf16x8*)(fb + ct * 128);
                bl[ct] = *(const bf16x8*)(fb + 8192 + ct * 128);
            }
#pragma unroll
            for (int ct = 0; ct < 2; ct++) {
                acc[ct] = __builtin_amdgcn_mfma_f32_16x16x32_bf16(ah[kc], bh[ct], acc[ct], 0, 0, 0);
                acc[ct] = __builtin_amdgcn_mfma_f32_16x16x32_bf16(al[kc], bh[ct], acc[ct], 0, 0, 0);
                acc[ct] = __builtin_amdgcn_mfma_f32_16x16x32_bf16(ah[kc], bl[ct], acc[ct], 0, 0, 0);
            }
        }

        // per-lane argmax update (ascending g, ascending ct; strict > keeps
        // the lowest cluster index among exact ties)
#pragma unroll
        for (int ct = 0; ct < 2; ct++) {
            int cbase = g * 32 + ct * 16 + m;
#pragma unroll
            for (int r = 0; r < 4; r++) {
                float v2 = acc[ct][r];
                if (v2 > bv[r]) { bv[r] = v2; bi[r] = cbase; }
            }
        }
        __syncthreads();   // next-group stage complete; buffer safe to reuse
    }

    // reduce across the 16 m-lanes; tie -> lowest cluster index
#pragma unroll
    for (int mask = 1; mask < 16; mask <<= 1) {
#pragma unroll
        for (int r = 0; r < 4; r++) {
            float ov = __shfl_xor(bv[r], mask, 64);
            int   oi = __shfl_xor(bi[r], mask, 64);
            if (ov > bv[r] || (ov == bv[r] && oi < bi[r])) { bv[r] = ov; bi[r] = oi; }
        }
    }
    if (m == 0) {
#pragma unroll
        for (int r = 0; r < 4; r++) {
            bkts[p0 + q * 4 + r] = (unsigned short)bi[r];   // point q*4+r of tile
        }
    }
#undef DMA_X
#undef READ_CVT
#undef DMA_MEANS
}

// ---------------------------------------------------------------------------
// K3: sort point indices by bucket (unchanged).
__global__ __launch_bounds__(256) void k_sort(const unsigned short* __restrict__ bkts,
                                              unsigned short* __restrict__ list,
                                              int* __restrict__ bins) {
    __shared__ int hist[256];
    __shared__ int base[256];
    __shared__ unsigned short lpos[1024];
    int t = threadIdx.x;
    hist[t] = 0;
    __syncthreads();
    int p0 = blockIdx.x * 1024;
    int bkt[4];
#pragma unroll
    for (int j = 0; j < 4; j++) {
        int p = p0 + j * 256 + t;
        int b = (int)bkts[p];
        bkt[j] = b;
        lpos[j * 256 + t] = (unsigned short)atomicAdd(&hist[b], 1);
    }
    __syncthreads();
    base[t] = hist[t] > 0 ? atomicAdd(&bins[t], hist[t]) : 0;
    __syncthreads();
#pragma unroll
    for (int j = 0; j < 4; j++) {
        int b = bkt[j];
        int slot = base[b] + (int)lpos[j * 256 + t];
        list[b * MAXN + slot] = (unsigned short)(p0 + j * 256 + t);
    }
}

// ---------------------------------------------------------------------------
// K4: gather partial sums (unchanged from R4). grid (256,4) -> 4 blocks/CU;
// each block writes a NON-atomic partial sum row into dead-workspace aliases.
__global__ __launch_bounds__(256) void k_gather(const float* __restrict__ x,
                                                const unsigned short* __restrict__ list,
                                                const int* __restrict__ bins,
                                                const float* __restrict__ inv_norm,
                                                float* __restrict__ ps0,
                                                float* __restrict__ ps1,
                                                float* __restrict__ ps2,
                                                float* __restrict__ ps3) {
    __shared__ int   plist[256];
    __shared__ float linv[256];
    int c = blockIdx.x, y = blockIdx.y, t = threadIdx.x;
    int cnt = bins[c];
    int i0 = (cnt * y) >> 2, i1 = (cnt * (y + 1)) >> 2;
    int n = i1 - i0;                       // <= 256 (cnt <= MAXN)
    for (int i = t; i < n; i += 256) {
        int p = (int)list[c * MAXN + i0 + i];
        plist[i] = p;
        linv[i]  = inv_norm[p];
    }
    __syncthreads();
    float s = 0.f;
    int i = 0;
    for (; i + 16 <= n; i += 16) {
        float xv[16], lv[16];
#pragma unroll
        for (int j = 0; j < 16; j++) {
            xv[j] = x[(size_t)plist[i + j] * DD + t];
            lv[j] = linv[i + j];
        }
#pragma unroll
        for (int j = 0; j < 16; j++) s += xv[j] * lv[j];
    }
    for (; i < n; i++) s += x[(size_t)plist[i] * DD + t] * linv[i];
    float* base = (y == 0) ? ps0 : (y == 1) ? ps1 : (y == 2) ? ps2 : ps3;
    base[c * DD + t] = s;
}

// ---------------------------------------------------------------------------
// K5: x_global = l2norm(sum of 4 partials) (or old mean if empty bin), then
// k = xg @ Wk^T, v = xg @ Wv^T in [h][c][dh] layout. All f32. 256 blocks.
// NOTE: ps3 aliases out[131072..196608) (x_global). Each thread reads
// ps3[c*DD+t] BEFORE writing out[131072+c*DD+t] at the SAME index -> safe.
__global__ __launch_bounds__(256) void k_xgkv(const float* __restrict__ ps0,
                                              const float* __restrict__ ps1,
                                              const float* __restrict__ ps2,
                                              const float* __restrict__ ps3,
                                              const int* __restrict__ bins,
                                              const float* __restrict__ means_n,
                                              const float* __restrict__ Wk,
                                              const float* __restrict__ Wv,
                                              float* __restrict__ out) {
    __shared__ float red[256];
    __shared__ __align__(16) float xr[256];
    int c = blockIdx.x, t = threadIdx.x;
    float s = ps0[c * DD + t] + ps1[c * DD + t] + ps2[c * DD + t] + ps3[c * DD + t];
    red[t] = s * s;
    __syncthreads();
    for (int off = 128; off > 0; off >>= 1) {
        if (t < off) red[t] += red[t + off];
        __syncthreads();
    }
    float g;
    if (bins[c] > 0) g = s / fmaxf(sqrtf(red[0]), 1e-12f);
    else             g = means_n[c * DD + t];
    out[131072 + c * DD + t] = g;   // output 2: x_global
    xr[t] = g;
    __syncthreads();

    float ak = 0.f, av = 0.f;
    const float4* wkp = (const float4*)(Wk + (size_t)t * DD);
    const float4* wvp = (const float4*)(Wv + (size_t)t * DD);
#pragma unroll 8
    for (int j4 = 0; j4 < 64; j4++) {
        float4 wk = wkp[j4], wv = wvp[j4];
        float4 a = *(const float4*)(xr + j4 * 4);
        ak += a.x * wk.x + a.y * wk.y + a.z * wk.z + a.w * wk.w;
        av += a.x * wv.x + a.y * wv.y + a.z * wv.z + a.w * wv.w;
    }
    int h = t >> 5, dh = t & 31;
    out[h * 8192 + c * 32 + dh]         = ak;   // output 0: k
    out[65536 + h * 8192 + c * 32 + dh] = av;   // output 1: v
}

// ---------------------------------------------------------------------------
extern "C" void kernel_launch(void* const* d_in, const int* in_sizes, int n_in,
                              void* d_out, int out_size, void* d_ws, size_t ws_size,
                              hipStream_t stream) {
    (void)in_sizes; (void)n_in; (void)out_size; (void)ws_size;
    const float* x  = (const float*)d_in[0];  // [16,4096,256] f32
    const float* xm = (const float*)d_in[1];  // [256,256] f32
    const float* Wk = (const float*)d_in[2];  // [256,256] f32
    const float* Wv = (const float*)d_in[3];  // [256,256] f32

    float* ws       = (float*)d_ws;
    float* means_n  = ws;                                        // [0,65536)
    float* inv_norm = ws + 65536;                                // [65536,131072)
    unsigned short* bkts = (unsigned short*)(ws + 131072);       // [131072,163840)
    int*   bins     = (int*)(ws + 262144);                       // [262144,262400)
    unsigned short* mpk2 = (unsigned short*)(ws + 262400);       // [262400,327936)
    unsigned short* list = (unsigned short*)(ws + 327936);       // [327936,459008)
    float* out      = (float*)d_out;
    // partial-sum rows alias memory that is dead by the time k_gather runs:
    float* ps0 = ws + 131072;    // bkts region (dead after k_sort)
    float* ps1 = ws + 196608;    // spare region
    float* ps2 = ws + 262400;    // mpk2 (dead after k_assign)
    float* ps3 = out + 131072;   // x_global slot (k_xgkv reads then overwrites)

    k_prep  <<<256, 256, 0, stream>>>(xm, means_n, mpk2, bins);
    k_assign<<<512, 512, 0, stream>>>(x, mpk2, bkts, inv_norm);
    k_sort  <<<64, 256, 0, stream>>>(bkts, list, bins);
    k_gather<<<dim3(256, 4), 256, 0, stream>>>(x, list, bins, inv_norm, ps0, ps1, ps2, ps3);
    k_xgkv  <<<256, 256, 0, stream>>>(ps0, ps1, ps2, ps3, bins, means_n, Wk, Wv, out);
}